// Round 6
// baseline (392.901 us; speedup 1.0000x reference)
//
#include <hip/hip_runtime.h>
#include <hip/hip_bf16.h>
#include <math.h>

#define BB 128
#define NN 12000
#define NIN 4000
#define NFN 7000
#define NOMIC 3600
#define FC 56000
#define EE 57000
#define LAT 100

typedef __hip_bfloat16 bf16;

__device__ __forceinline__ ushort f2bf(float f) {
  bf16 h = __float2bfloat16(f);
  return *(ushort*)&h;
}
__device__ __forceinline__ float bf2f(ushort u) {
  bf16 h = *(bf16*)&u;
  return __bfloat162float(h);
}

// ---------------- transpose x (B,N) -> xT (N,B) ----------------
__global__ void k_transpose(const float* __restrict__ x, float* __restrict__ xT) {
  __shared__ float t[32][33];
  int n0 = blockIdx.x * 32, b0 = blockIdx.y * 32;
  int tx = threadIdx.x, ty = threadIdx.y;
#pragma unroll
  for (int s = 0; s < 4; s++) {
    int b = b0 + ty + s * 8;
    int n = n0 + tx;
    t[ty + s * 8][tx] = x[b * NN + n];
  }
  __syncthreads();
#pragma unroll
  for (int s = 0; s < 4; s++) {
    int n = n0 + ty + s * 8;
    int b = b0 + tx;
    xT[n * BB + b] = t[tx][ty + s * 8];
  }
}

// ---------------- AE layer 1: h[j*128+b], split-K, W1 wave-uniform float4 ----------------
__global__ void k_ae1(const float* __restrict__ xT, const float* __restrict__ W1,
                      float* __restrict__ h) {
  int b = threadIdx.x;
  int j0 = blockIdx.x * 4;
  int k0 = blockIdx.y * 180;
  float acc0 = 0.f, acc1 = 0.f, acc2 = 0.f, acc3 = 0.f;
  const float* xp = &xT[(size_t)k0 * BB + b];
  const float* wp = &W1[(size_t)k0 * LAT + j0];
#pragma unroll 4
  for (int kk = 0; kk < 180; kk++) {
    float xv = xp[kk * BB];
    float4 w = *(const float4*)(wp + kk * LAT);
    acc0 += xv * w.x; acc1 += xv * w.y; acc2 += xv * w.z; acc3 += xv * w.w;
  }
  atomicAdd(&h[(j0 + 0) * BB + b], acc0);
  atomicAdd(&h[(j0 + 1) * BB + b], acc1);
  atomicAdd(&h[(j0 + 2) * BB + b], acc2);
  atomicAdd(&h[(j0 + 3) * BB + b], acc3);
}

// ---------------- build xeT (bf16) from xT / src ----------------
__global__ void k_build_xe(const float* __restrict__ xT, const int* __restrict__ src,
                           ushort* __restrict__ xeT) {
  int idx = blockIdx.x * 256 + threadIdx.x;
  if (idx >= EE * BB) return;
  int e = idx >> 7, b = idx & 127;
  int s = src[e];
  xeT[idx] = (s < NOMIC) ? f2bf(0.f) : f2bf(xT[s * BB + b]);
}

// ---------------- map[e] = fe-position i (else -1, pre-set by memset 0xFF) ----------------
__global__ void k_map(const int* __restrict__ w3_cols, int* __restrict__ map, int n_fe) {
  int i = blockIdx.x * 256 + threadIdx.x;
  if (i < n_fe) map[w3_cols[i * 8]] = i;
}

// ---------------- AE layer 2 GEMM: zT(bf16) = elu(h) @ W2 + b2, + LN partial sums --------
// Block = 64 b x 128 j (hh 25.6 KB -> 4 blocks/CU wave-capped), grid 876, 512 thr.
// Thread = 2b x 8j. W2 loads wave-broadcast; hh b64 reads 2-way (free); stores coalesce.
__launch_bounds__(512)
__global__ void k_ae2(const float* __restrict__ h_raw, const float* __restrict__ b_ae1,
                      const float* __restrict__ W2, const float* __restrict__ b_ae2,
                      ushort* __restrict__ zT, float* __restrict__ red) {
  __shared__ __align__(16) float hh[LAT * 64];  // [k*64 + bl], 25.6 KB
  __shared__ float lred[128];
  int tid = threadIdx.x;
  int jb = blockIdx.x >> 1;   // j-tile 0..437
  int b0 = (blockIdx.x & 1) * 64;
  if (tid < 128) lred[tid] = 0.f;
  for (int idx = tid; idx < LAT * 64; idx += 512) {
    int k = idx >> 6, bl = idx & 63;
    float v = h_raw[k * BB + b0 + bl] + b_ae1[k];
    v = v > 0.f ? v : expm1f(v);
    hh[idx] = v;
  }
  __syncthreads();

  int tj = tid >> 5;   // 0..15 -> 8 j each
  int tb = tid & 31;   // 0..31 -> 2 b each
  int j0 = jb * 128;
  if (j0 + 128 > FC) j0 = FC - 128;  // last tile overlaps prev by 64 j
  bool cred = (jb < 437) || (tj >= 8);  // unique-j guard for LN sums

  float acc[2][8];
#pragma unroll
  for (int i = 0; i < 2; i++)
#pragma unroll
    for (int j = 0; j < 8; j++) acc[i][j] = 0.f;

  const float* hp = &hh[tb * 2];
  const float* wp = &W2[j0 + tj * 8];
#pragma unroll 4
  for (int k = 0; k < LAT; k++) {
    float2 h0 = *(const float2*)(hp + k * 64);
    float4 w0 = *(const float4*)(wp + (size_t)k * FC);
    float4 w1 = *(const float4*)(wp + (size_t)k * FC + 4);
    float aw[8] = {w0.x, w0.y, w0.z, w0.w, w1.x, w1.y, w1.z, w1.w};
#pragma unroll
    for (int j = 0; j < 8; j++) {
      acc[0][j] += h0.x * aw[j];
      acc[1][j] += h0.y * aw[j];
    }
  }

  float4 bb0 = *(const float4*)&b_ae2[j0 + tj * 8];
  float4 bb1 = *(const float4*)&b_ae2[j0 + tj * 8 + 4];
  float bw[8] = {bb0.x, bb0.y, bb0.z, bb0.w, bb1.x, bb1.y, bb1.z, bb1.w};
#pragma unroll
  for (int i = 0; i < 2; i++)
#pragma unroll
    for (int j = 0; j < 8; j++) acc[i][j] += bw[j];

  // store zT bf16: lanes tb 0..31 x ushort2 = 128 B contiguous per j
#pragma unroll
  for (int j = 0; j < 8; j++) {
    ushort2 pk;
    pk.x = f2bf(acc[0][j]);
    pk.y = f2bf(acc[1][j]);
    *(ushort2*)&zT[(size_t)(j0 + tj * 8 + j) * BB + b0 + tb * 2] = pk;
  }

  if (cred) {
#pragma unroll
    for (int i = 0; i < 2; i++) {
      float s = 0.f, q = 0.f;
#pragma unroll
      for (int j = 0; j < 8; j++) { s += acc[i][j]; q += acc[i][j] * acc[i][j]; }
      int bl = tb * 2 + i;
      atomicAdd(&lred[bl * 2], s);
      atomicAdd(&lred[bl * 2 + 1], q);
    }
  }
  __syncthreads();
  if (tid < 128) atomicAdd(&red[b0 * 2 + tid], lred[tid]);
}

// ---------------- layer part 1: hfc = elu(s * groupLN(8x8 matmul(xe) + b1)) -------------
// s computed inline: s = sigmoid((z - mu)*isg), mu/isg from red sums (k_s/k_stat fused).
__launch_bounds__(256)
__global__ void k_layer1(const ushort* __restrict__ xeT, const float* __restrict__ w1l,
                         const float* __restrict__ b1l, const ushort* __restrict__ zT,
                         const float* __restrict__ red, ushort* __restrict__ hfcT) {
  __shared__ __align__(16) float wsm[2][64];
  __shared__ float bsm[2][8];
  int tid = threadIdx.x;
  int fs = tid >> 7;
  int b = tid & 127;
  int f = blockIdx.x * 2 + fs;
  if (tid < 128) wsm[tid >> 6][tid & 63] = w1l[blockIdx.x * 128 + tid];
  if (tid >= 128 && tid < 144) {
    int q = tid - 128;
    bsm[q >> 3][q & 7] = b1l[blockIdx.x * 16 + q];
  }
  __syncthreads();
  // global-LN stats for this batch lane
  float mu_ln = red[b * 2] * (1.f / FC);
  float var_ln = red[b * 2 + 1] * (1.f / FC) - mu_ln * mu_ln;
  float isg_ln = rsqrtf(var_ln + 1e-5f);

  float xv[8];
#pragma unroll
  for (int k = 0; k < 8; k++) xv[k] = bf2f(xeT[(f * 8 + k) * BB + b]);
  float acc[8];
#pragma unroll
  for (int c = 0; c < 8; c++) acc[c] = bsm[fs][c];
#pragma unroll
  for (int k = 0; k < 8; k++) {
    const float4* wp = (const float4*)&wsm[fs][k * 8];
    float4 w0 = wp[0], w1 = wp[1];
    acc[0] += xv[k] * w0.x; acc[1] += xv[k] * w0.y;
    acc[2] += xv[k] * w0.z; acc[3] += xv[k] * w0.w;
    acc[4] += xv[k] * w1.x; acc[5] += xv[k] * w1.y;
    acc[6] += xv[k] * w1.z; acc[7] += xv[k] * w1.w;
  }
  float mu = 0.f;
#pragma unroll
  for (int c = 0; c < 8; c++) mu += acc[c];
  mu *= 0.125f;
  float var = 0.f;
#pragma unroll
  for (int c = 0; c < 8; c++) { float d = acc[c] - mu; var += d * d; }
  var *= 0.125f;
  float sc = rsqrtf(var + 1e-5f);
#pragma unroll
  for (int c = 0; c < 8; c++) {
    float v = (acc[c] - mu) * sc;
    float zv = bf2f(zT[(f * 8 + c) * BB + b]);
    float sv = 1.f / (1.f + expf(-(zv - mu_ln) * isg_ln));
    float hv = sv * v;
    hv = hv > 0.f ? hv : expm1f(hv);
    hfcT[(f * 8 + c) * BB + b] = f2bf(hv);
  }
}

// ---------------- layer part 2: xe = (fe? dot8(hfc[src], w3) : 0) + b3 + xe ----------------
__launch_bounds__(256)
__global__ void k_layer2(const ushort* __restrict__ hfcT, const float* __restrict__ w3l,
                         const float* __restrict__ b3l, const int* __restrict__ map,
                         const int* __restrict__ src, ushort* __restrict__ xeT) {
  __shared__ float wsm[2][8];
  int tid = threadIdx.x;
  int es = tid >> 7;
  int b = tid & 127;
  int e = blockIdx.x * 2 + es;
  if (tid < 16) {
    int q = tid;
    int ee = blockIdx.x * 2 + (q >> 3);
    int ii = map[ee];
    wsm[q >> 3][q & 7] = (ii >= 0) ? w3l[ii * 8 + (q & 7)] : 0.f;
  }
  __syncthreads();
  int i = map[e];
  float rv = b3l[e] + bf2f(xeT[e * BB + b]);
  if (i >= 0) {
    int g = src[e] - NIN;
    float a = 0.f;
#pragma unroll
    for (int c = 0; c < 8; c++)
      a += bf2f(hfcT[(g * 8 + c) * BB + b]) * wsm[es][c];
    rv += a;
  }
  xeT[e * BB + b] = f2bf(rv);
}

// ---------------- output: out[b, 11000+j] = xe[b, 56000+j] / 4 ----------------
__global__ void k_out(const ushort* __restrict__ xeT, float* __restrict__ out) {
  __shared__ float t[32][33];
  int j0 = blockIdx.x * 32, b0 = blockIdx.y * 32;
  int tx = threadIdx.x, ty = threadIdx.y;
#pragma unroll
  for (int s2 = 0; s2 < 4; s2++) {
    int j = j0 + ty + s2 * 8;
    if (j < 1000) t[ty + s2 * 8][tx] = bf2f(xeT[(FC + j) * BB + b0 + tx]);
  }
  __syncthreads();
#pragma unroll
  for (int s2 = 0; s2 < 4; s2++) {
    int b = b0 + ty + s2 * 8;
    int j = j0 + tx;
    if (j < 1000) out[b * NN + 11000 + j] = t[tx][ty + s2 * 8] * 0.25f;
  }
}

extern "C" void kernel_launch(void* const* d_in, const int* in_sizes, int n_in,
                              void* d_out, int out_size, void* d_ws, size_t ws_size,
                              hipStream_t stream) {
  const float* x = (const float*)d_in[0];
  const float* W_ae1 = (const float*)d_in[1];
  const float* b_ae1 = (const float*)d_in[2];
  const float* W_ae2 = (const float*)d_in[3];
  const float* b_ae2 = (const float*)d_in[4];
  const float* w1_vals = (const float*)d_in[5];
  const float* b1 = (const float*)d_in[6];
  const float* w3_vals = (const float*)d_in[7];
  const float* b3 = (const float*)d_in[8];
  const int* src = (const int*)d_in[9];
  const int* w3_cols = (const int*)d_in[14];

  int nnz3 = in_sizes[13];
  int n_fe = nnz3 / 8;

  // Workspace layout (f32 slot offsets); bf16 tensors occupy elems/2 slots.
  float* W = (float*)d_ws;
  float* h_raw = W + 0;                  // 12,800  [j*128+b]
  float* red = W + 12800;                // 256
  int* map = (int*)(W + 13312);          // 57,000 ints -> ends 70,312
  float* xT = W + 70400;                 // 1,536,000 -> ends 1,606,400
  ushort* xeT = (ushort*)(W + 1606400);  // 3,648,000 slots -> ends 5,254,400
  ushort* zT = (ushort*)(W + 5254400);   // 3,584,000 slots -> ends 8,838,400
  ushort* hfcT = (ushort*)(W + 8838400); // 3,584,000 slots -> ends 12,422,400

  hipMemsetAsync(h_raw, 0, 13056 * sizeof(float), stream);  // h_raw + red
  hipMemsetAsync(map, 0xFF, EE * sizeof(int), stream);
  hipMemsetAsync(d_out, 0, (size_t)out_size * sizeof(float), stream);

  k_transpose<<<dim3(NN / 32, BB / 32), dim3(32, 8), 0, stream>>>(x, xT);
  k_ae1<<<dim3(25, 20), 128, 0, stream>>>(xT, W_ae1, h_raw);
  k_build_xe<<<(EE * BB) / 256, 256, 0, stream>>>(xT, src, xeT);
  k_map<<<(n_fe + 255) / 256, 256, 0, stream>>>(w3_cols, map, n_fe);
  k_ae2<<<876, 512, 0, stream>>>(h_raw, b_ae1, W_ae2, b_ae2, zT, red);
  for (int l = 0; l < 4; l++) {
    k_layer1<<<NFN / 2, 256, 0, stream>>>(xeT, w1_vals + (size_t)l * 448000,
                                          b1 + (size_t)l * FC, zT, red, hfcT);
    k_layer2<<<EE / 2, 256, 0, stream>>>(hfcT, w3_vals + (size_t)l * nnz3,
                                         b3 + (size_t)l * EE, map, src, xeT);
  }
  k_out<<<dim3(32, 4), dim3(32, 8), 0, stream>>>(xeT, (float*)d_out);
}

// Round 7
// 390.838 us; speedup vs baseline: 1.0053x; 1.0053x over previous
//
#include <hip/hip_runtime.h>
#include <hip/hip_bf16.h>
#include <math.h>

#define BB 128
#define NN 12000
#define NIN 4000
#define NFN 7000
#define NOMIC 3600
#define FC 56000
#define EE 57000
#define LAT 100

typedef __hip_bfloat16 bf16;

__device__ __forceinline__ ushort f2bf(float f) {
  bf16 h = __float2bfloat16(f);
  return *(ushort*)&h;
}
__device__ __forceinline__ float bf2f(ushort u) {
  bf16 h = *(bf16*)&u;
  return __bfloat162float(h);
}

// ---------------- transpose x (B,N) -> xT (N,B) ----------------
__global__ void k_transpose(const float* __restrict__ x, float* __restrict__ xT) {
  __shared__ float t[32][33];
  int n0 = blockIdx.x * 32, b0 = blockIdx.y * 32;
  int tx = threadIdx.x, ty = threadIdx.y;
#pragma unroll
  for (int s = 0; s < 4; s++) {
    int b = b0 + ty + s * 8;
    int n = n0 + tx;
    t[ty + s * 8][tx] = x[b * NN + n];
  }
  __syncthreads();
#pragma unroll
  for (int s = 0; s < 4; s++) {
    int n = n0 + ty + s * 8;
    int b = b0 + tx;
    xT[n * BB + b] = t[tx][ty + s * 8];
  }
}

// ---------------- AE layer 1: h[j*128+b], split-K, W1 wave-uniform float4 ----------------
// grid (25 j-quads, 40 k-chunks of 90) -> 1000 blocks x 2 waves.
__global__ void k_ae1(const float* __restrict__ xT, const float* __restrict__ W1,
                      float* __restrict__ h) {
  int b = threadIdx.x;
  int j0 = blockIdx.x * 4;
  int k0 = blockIdx.y * 90;
  float acc0 = 0.f, acc1 = 0.f, acc2 = 0.f, acc3 = 0.f;
  const float* xp = &xT[(size_t)k0 * BB + b];
  const float* wp = &W1[(size_t)k0 * LAT + j0];
#pragma unroll 6
  for (int kk = 0; kk < 90; kk++) {
    float xv = xp[kk * BB];
    float4 w = *(const float4*)(wp + kk * LAT);
    acc0 += xv * w.x; acc1 += xv * w.y; acc2 += xv * w.z; acc3 += xv * w.w;
  }
  atomicAdd(&h[(j0 + 0) * BB + b], acc0);
  atomicAdd(&h[(j0 + 1) * BB + b], acc1);
  atomicAdd(&h[(j0 + 2) * BB + b], acc2);
  atomicAdd(&h[(j0 + 3) * BB + b], acc3);
}

// ---------------- elu(h + b_ae1) in place (hoisted out of k_ae2's 875 blocks) ----------
__global__ void k_elu(float* __restrict__ h, const float* __restrict__ b_ae1) {
  int i = blockIdx.x * 256 + threadIdx.x;  // 12800 total
  float v = h[i] + b_ae1[i >> 7];
  h[i] = v > 0.f ? v : expm1f(v);
}

// ---------------- build xeT (bf16) from xT / src ----------------
__global__ void k_build_xe(const float* __restrict__ xT, const int* __restrict__ src,
                           ushort* __restrict__ xeT) {
  int idx = blockIdx.x * 256 + threadIdx.x;
  if (idx >= EE * BB) return;
  int e = idx >> 7, b = idx & 127;
  int s = src[e];
  xeT[idx] = (s < NOMIC) ? f2bf(0.f) : f2bf(xT[s * BB + b]);
}

// ---------------- map[e] = fe-position i (else -1, pre-set by memset 0xFF) ----------------
__global__ void k_map(const int* __restrict__ w3_cols, int* __restrict__ map, int n_fe) {
  int i = blockIdx.x * 256 + threadIdx.x;
  if (i < n_fe) map[w3_cols[i * 8]] = i;
}

// ---------------- AE layer 2 GEMM: zT(bf16) = h_elu @ W2 + b2, + LN partial sums --------
// Tile 128b x 64j, 256 thr = 8 tj x 32 tb, 4b x 8j per thread (32 FMA : 2 VMEM).
// Grid 875 (j split only -> W2 fetched once). hh 51.2 KB -> 3 blocks/CU.
__launch_bounds__(256)
__global__ void k_ae2(const float* __restrict__ h_elu, const float* __restrict__ W2,
                      const float* __restrict__ b_ae2, ushort* __restrict__ zT,
                      float* __restrict__ red) {
  __shared__ __align__(16) float hh[LAT * BB];  // [k*128+b], 51.2 KB
  __shared__ float lred[256];
  int tid = threadIdx.x;
  lred[tid] = 0.f;
  for (int i = tid * 4; i < LAT * BB; i += 256 * 4)
    *(float4*)&hh[i] = *(const float4*)&h_elu[i];
  __syncthreads();

  int tj = tid >> 5;   // 0..7  -> 8 j each
  int tb = tid & 31;   // 0..31 -> 4 b each
  int j0 = blockIdx.x * 64;  // 875 * 64 = 56000 exact

  float acc[4][8];
#pragma unroll
  for (int i = 0; i < 4; i++)
#pragma unroll
    for (int j = 0; j < 8; j++) acc[i][j] = 0.f;

  const float* hp = &hh[tb * 4];
  const float* wp = &W2[j0 + tj * 8];
#pragma unroll 4
  for (int k = 0; k < LAT; k++) {
    float4 h0 = *(const float4*)(hp + k * BB);
    float4 w0 = *(const float4*)(wp + (size_t)k * FC);
    float4 w1 = *(const float4*)(wp + (size_t)k * FC + 4);
    float ah[4] = {h0.x, h0.y, h0.z, h0.w};
    float aw[8] = {w0.x, w0.y, w0.z, w0.w, w1.x, w1.y, w1.z, w1.w};
#pragma unroll
    for (int i = 0; i < 4; i++)
#pragma unroll
      for (int j = 0; j < 8; j++) acc[i][j] += ah[i] * aw[j];
  }

  float4 bb0 = *(const float4*)&b_ae2[j0 + tj * 8];
  float4 bb1 = *(const float4*)&b_ae2[j0 + tj * 8 + 4];
  float bw[8] = {bb0.x, bb0.y, bb0.z, bb0.w, bb1.x, bb1.y, bb1.z, bb1.w};
#pragma unroll
  for (int i = 0; i < 4; i++)
#pragma unroll
    for (int j = 0; j < 8; j++) acc[i][j] += bw[j];

  // store zT bf16: per j, 32 lanes x ushort4 = 256 B contiguous
#pragma unroll
  for (int j = 0; j < 8; j++) {
    ushort4 pk;
    pk.x = f2bf(acc[0][j]); pk.y = f2bf(acc[1][j]);
    pk.z = f2bf(acc[2][j]); pk.w = f2bf(acc[3][j]);
    *(ushort4*)&zT[(size_t)(j0 + tj * 8 + j) * BB + tb * 4] = pk;
  }

  // LN partial sums (each j counted once: tiles are exact)
#pragma unroll
  for (int i = 0; i < 4; i++) {
    float s = 0.f, q = 0.f;
#pragma unroll
    for (int j = 0; j < 8; j++) { s += acc[i][j]; q += acc[i][j] * acc[i][j]; }
    int b = tb * 4 + i;
    atomicAdd(&lred[b * 2], s);
    atomicAdd(&lred[b * 2 + 1], q);
  }
  __syncthreads();
  atomicAdd(&red[tid], lred[tid]);
}

// ---------------- layer part 1: hfc = elu(s * groupLN(8x8 matmul(xe) + b1)) -------------
// s computed inline: s = sigmoid((z - mu)*isg), mu/isg from red sums.
__launch_bounds__(256)
__global__ void k_layer1(const ushort* __restrict__ xeT, const float* __restrict__ w1l,
                         const float* __restrict__ b1l, const ushort* __restrict__ zT,
                         const float* __restrict__ red, ushort* __restrict__ hfcT) {
  __shared__ __align__(16) float wsm[2][64];
  __shared__ float bsm[2][8];
  int tid = threadIdx.x;
  int fs = tid >> 7;
  int b = tid & 127;
  int f = blockIdx.x * 2 + fs;
  if (tid < 128) wsm[tid >> 6][tid & 63] = w1l[blockIdx.x * 128 + tid];
  if (tid >= 128 && tid < 144) {
    int q = tid - 128;
    bsm[q >> 3][q & 7] = b1l[blockIdx.x * 16 + q];
  }
  __syncthreads();
  float mu_ln = red[b * 2] * (1.f / FC);
  float var_ln = red[b * 2 + 1] * (1.f / FC) - mu_ln * mu_ln;
  float isg_ln = rsqrtf(var_ln + 1e-5f);

  float xv[8];
#pragma unroll
  for (int k = 0; k < 8; k++) xv[k] = bf2f(xeT[(f * 8 + k) * BB + b]);
  float acc[8];
#pragma unroll
  for (int c = 0; c < 8; c++) acc[c] = bsm[fs][c];
#pragma unroll
  for (int k = 0; k < 8; k++) {
    const float4* wp = (const float4*)&wsm[fs][k * 8];
    float4 w0 = wp[0], w1 = wp[1];
    acc[0] += xv[k] * w0.x; acc[1] += xv[k] * w0.y;
    acc[2] += xv[k] * w0.z; acc[3] += xv[k] * w0.w;
    acc[4] += xv[k] * w1.x; acc[5] += xv[k] * w1.y;
    acc[6] += xv[k] * w1.z; acc[7] += xv[k] * w1.w;
  }
  float mu = 0.f;
#pragma unroll
  for (int c = 0; c < 8; c++) mu += acc[c];
  mu *= 0.125f;
  float var = 0.f;
#pragma unroll
  for (int c = 0; c < 8; c++) { float d = acc[c] - mu; var += d * d; }
  var *= 0.125f;
  float sc = rsqrtf(var + 1e-5f);
#pragma unroll
  for (int c = 0; c < 8; c++) {
    float v = (acc[c] - mu) * sc;
    float zv = bf2f(zT[(f * 8 + c) * BB + b]);
    float sv = 1.f / (1.f + expf(-(zv - mu_ln) * isg_ln));
    float hv = sv * v;
    hv = hv > 0.f ? hv : expm1f(hv);
    hfcT[(f * 8 + c) * BB + b] = f2bf(hv);
  }
}

// ---------------- layer part 2: xe = (fe? dot8(hfc[src], w3) : 0) + b3 + xe ----------------
__launch_bounds__(256)
__global__ void k_layer2(const ushort* __restrict__ hfcT, const float* __restrict__ w3l,
                         const float* __restrict__ b3l, const int* __restrict__ map,
                         const int* __restrict__ src, ushort* __restrict__ xeT) {
  __shared__ float wsm[2][8];
  int tid = threadIdx.x;
  int es = tid >> 7;
  int b = tid & 127;
  int e = blockIdx.x * 2 + es;
  if (tid < 16) {
    int q = tid;
    int ee = blockIdx.x * 2 + (q >> 3);
    int ii = map[ee];
    wsm[q >> 3][q & 7] = (ii >= 0) ? w3l[ii * 8 + (q & 7)] : 0.f;
  }
  __syncthreads();
  int i = map[e];
  float rv = b3l[e] + bf2f(xeT[e * BB + b]);
  if (i >= 0) {
    int g = src[e] - NIN;
    float a = 0.f;
#pragma unroll
    for (int c = 0; c < 8; c++)
      a += bf2f(hfcT[(g * 8 + c) * BB + b]) * wsm[es][c];
    rv += a;
  }
  xeT[e * BB + b] = f2bf(rv);
}

// ---------------- output: out[b, 11000+j] = xe[b, 56000+j] / 4 ----------------
__global__ void k_out(const ushort* __restrict__ xeT, float* __restrict__ out) {
  __shared__ float t[32][33];
  int j0 = blockIdx.x * 32, b0 = blockIdx.y * 32;
  int tx = threadIdx.x, ty = threadIdx.y;
#pragma unroll
  for (int s2 = 0; s2 < 4; s2++) {
    int j = j0 + ty + s2 * 8;
    if (j < 1000) t[ty + s2 * 8][tx] = bf2f(xeT[(FC + j) * BB + b0 + tx]);
  }
  __syncthreads();
#pragma unroll
  for (int s2 = 0; s2 < 4; s2++) {
    int b = b0 + ty + s2 * 8;
    int j = j0 + tx;
    if (j < 1000) out[b * NN + 11000 + j] = t[tx][ty + s2 * 8] * 0.25f;
  }
}

extern "C" void kernel_launch(void* const* d_in, const int* in_sizes, int n_in,
                              void* d_out, int out_size, void* d_ws, size_t ws_size,
                              hipStream_t stream) {
  const float* x = (const float*)d_in[0];
  const float* W_ae1 = (const float*)d_in[1];
  const float* b_ae1 = (const float*)d_in[2];
  const float* W_ae2 = (const float*)d_in[3];
  const float* b_ae2 = (const float*)d_in[4];
  const float* w1_vals = (const float*)d_in[5];
  const float* b1 = (const float*)d_in[6];
  const float* w3_vals = (const float*)d_in[7];
  const float* b3 = (const float*)d_in[8];
  const int* src = (const int*)d_in[9];
  const int* w3_cols = (const int*)d_in[14];

  int nnz3 = in_sizes[13];
  int n_fe = nnz3 / 8;

  // Workspace layout (f32 slot offsets); bf16 tensors occupy elems/2 slots.
  float* W = (float*)d_ws;
  float* h_raw = W + 0;                  // 12,800  [j*128+b]
  float* red = W + 12800;                // 256
  int* map = (int*)(W + 13312);          // 57,000 ints -> ends 70,312
  float* xT = W + 70400;                 // 1,536,000 -> ends 1,606,400
  ushort* xeT = (ushort*)(W + 1606400);  // 3,648,000 slots -> ends 5,254,400
  ushort* zT = (ushort*)(W + 5254400);   // 3,584,000 slots -> ends 8,838,400
  ushort* hfcT = (ushort*)(W + 8838400); // 3,584,000 slots -> ends 12,422,400

  hipMemsetAsync(h_raw, 0, 13056 * sizeof(float), stream);  // h_raw + red
  hipMemsetAsync(map, 0xFF, EE * sizeof(int), stream);
  hipMemsetAsync(d_out, 0, (size_t)out_size * sizeof(float), stream);

  k_transpose<<<dim3(NN / 32, BB / 32), dim3(32, 8), 0, stream>>>(x, xT);
  k_ae1<<<dim3(25, 40), 128, 0, stream>>>(xT, W_ae1, h_raw);
  k_build_xe<<<(EE * BB) / 256, 256, 0, stream>>>(xT, src, xeT);
  k_map<<<(n_fe + 255) / 256, 256, 0, stream>>>(w3_cols, map, n_fe);
  k_elu<<<50, 256, 0, stream>>>(h_raw, b_ae1);
  k_ae2<<<875, 256, 0, stream>>>(h_raw, W_ae2, b_ae2, zT, red);
  for (int l = 0; l < 4; l++) {
    k_layer1<<<NFN / 2, 256, 0, stream>>>(xeT, w1_vals + (size_t)l * 448000,
                                          b1 + (size_t)l * FC, zT, red, hfcT);
    k_layer2<<<EE / 2, 256, 0, stream>>>(hfcT, w3_vals + (size_t)l * nnz3,
                                         b3 + (size_t)l * EE, map, src, xeT);
  }
  k_out<<<dim3(32, 4), dim3(32, 8), 0, stream>>>(xeT, (float*)d_out);
}

// Round 8
// 364.097 us; speedup vs baseline: 1.0791x; 1.0734x over previous
//
#include <hip/hip_runtime.h>
#include <hip/hip_bf16.h>
#include <math.h>

#define BB 128
#define NN 12000
#define NIN 4000
#define NFN 7000
#define NOMIC 3600
#define FC 56000
#define EE 57000
#define LAT 100

typedef __hip_bfloat16 bf16;

__device__ __forceinline__ ushort f2bf(float f) {
  bf16 h = __float2bfloat16(f);
  return *(ushort*)&h;
}
__device__ __forceinline__ float bf2f(ushort u) {
  bf16 h = *(bf16*)&u;
  return __bfloat162float(h);
}

// ---------------- transpose x (B,N) -> xT (N,B) ----------------
__global__ void k_transpose(const float* __restrict__ x, float* __restrict__ xT) {
  __shared__ float t[32][33];
  int n0 = blockIdx.x * 32, b0 = blockIdx.y * 32;
  int tx = threadIdx.x, ty = threadIdx.y;
#pragma unroll
  for (int s = 0; s < 4; s++) {
    int b = b0 + ty + s * 8;
    int n = n0 + tx;
    t[ty + s * 8][tx] = x[b * NN + n];
  }
  __syncthreads();
#pragma unroll
  for (int s = 0; s < 4; s++) {
    int n = n0 + ty + s * 8;
    int b = b0 + tx;
    xT[n * BB + b] = t[tx][ty + s * 8];
  }
}

// ---------------- AE layer 1: h[j*128+b], split-K, W1 wave-uniform float4 ----------------
__global__ void k_ae1(const float* __restrict__ xT, const float* __restrict__ W1,
                      float* __restrict__ h) {
  int b = threadIdx.x;
  int j0 = blockIdx.x * 4;
  int k0 = blockIdx.y * 90;
  float acc0 = 0.f, acc1 = 0.f, acc2 = 0.f, acc3 = 0.f;
  const float* xp = &xT[(size_t)k0 * BB + b];
  const float* wp = &W1[(size_t)k0 * LAT + j0];
#pragma unroll 6
  for (int kk = 0; kk < 90; kk++) {
    float xv = xp[kk * BB];
    float4 w = *(const float4*)(wp + kk * LAT);
    acc0 += xv * w.x; acc1 += xv * w.y; acc2 += xv * w.z; acc3 += xv * w.w;
  }
  atomicAdd(&h[(j0 + 0) * BB + b], acc0);
  atomicAdd(&h[(j0 + 1) * BB + b], acc1);
  atomicAdd(&h[(j0 + 2) * BB + b], acc2);
  atomicAdd(&h[(j0 + 3) * BB + b], acc3);
}

// ---------------- W2 fp32 -> bf16 (one-time, layout unchanged [k][j]) ----------------
__global__ void k_w2bf(const float* __restrict__ W2, ushort* __restrict__ w2b) {
  int i = (blockIdx.x * 256 + threadIdx.x) * 8;
  if (i >= LAT * FC) return;
  float4 a0 = *(const float4*)&W2[i];
  float4 a1 = *(const float4*)&W2[i + 4];
  union { ushort u[8]; uint4 v; } p;
  p.u[0] = f2bf(a0.x); p.u[1] = f2bf(a0.y); p.u[2] = f2bf(a0.z); p.u[3] = f2bf(a0.w);
  p.u[4] = f2bf(a1.x); p.u[5] = f2bf(a1.y); p.u[6] = f2bf(a1.z); p.u[7] = f2bf(a1.w);
  *(uint4*)&w2b[i] = p.v;
}

// ---------------- elu(h + b_ae1) -> bf16 hbf ----------------
__global__ void k_elu(const float* __restrict__ h, const float* __restrict__ b_ae1,
                      ushort* __restrict__ hbf) {
  int i = blockIdx.x * 256 + threadIdx.x;  // 12800 total
  float v = h[i] + b_ae1[i >> 7];
  hbf[i] = f2bf(v > 0.f ? v : expm1f(v));
}

// ---------------- build xeT (bf16) from xT / src ----------------
__global__ void k_build_xe(const float* __restrict__ xT, const int* __restrict__ src,
                           ushort* __restrict__ xeT) {
  int idx = blockIdx.x * 256 + threadIdx.x;
  if (idx >= EE * BB) return;
  int e = idx >> 7, b = idx & 127;
  int s = src[e];
  xeT[idx] = (s < NOMIC) ? f2bf(0.f) : f2bf(xT[s * BB + b]);
}

// ---------------- map[e] = fe-position i (else -1, pre-set by memset 0xFF) ----------------
__global__ void k_map(const int* __restrict__ w3_cols, int* __restrict__ map, int n_fe) {
  int i = blockIdx.x * 256 + threadIdx.x;
  if (i < n_fe) map[w3_cols[i * 8]] = i;
}

// ---------------- AE layer 2 GEMM: zT[f][b][c](bf16) = h_elu @ W2 + b2, + LN sums -------
// r5-proven shape: 438 blocks x 512 thr, tile 128b x 128j, 4b x 8j per thread.
// bf16 W2 (1 dwordx4/thread/k) + bf16 hh (25.6 KB LDS -> 4 blocks/CU wave-capped).
__launch_bounds__(512)
__global__ void k_ae2(const ushort* __restrict__ hbf, const ushort* __restrict__ w2b,
                      const float* __restrict__ b_ae2, uint4* __restrict__ zT4,
                      float* __restrict__ red) {
  __shared__ __align__(16) ushort hh[LAT * BB];  // [k*128+b] bf16, 25.6 KB
  __shared__ float lred[256];
  int tid = threadIdx.x;
  if (tid < 256) lred[tid] = 0.f;
  for (int i = tid * 8; i < LAT * BB; i += 512 * 8)
    *(uint4*)&hh[i] = *(const uint4*)&hbf[i];
  __syncthreads();

  int tj = tid >> 5;   // 0..15 -> 8 j (= 1 f node) each
  int tb = tid & 31;   // 0..31 -> 4 b each
  int j0 = blockIdx.x * 128;
  if (j0 + 128 > FC) j0 = FC - 128;        // last tile overlaps (grid 438)
  bool cred = (blockIdx.x < 437) || (tj >= 8);

  float acc[4][8];
#pragma unroll
  for (int i = 0; i < 4; i++)
#pragma unroll
    for (int j = 0; j < 8; j++) acc[i][j] = 0.f;

  const ushort* hp = &hh[tb * 4];
  const ushort* wp = &w2b[j0 + tj * 8];
#pragma unroll 4
  for (int k = 0; k < LAT; k++) {
    ushort4 h4 = *(const ushort4*)(hp + k * BB);
    union { ushort u[8]; uint4 v; } w8;
    w8.v = *(const uint4*)(wp + (size_t)k * FC);
    float ah[4] = {bf2f(h4.x), bf2f(h4.y), bf2f(h4.z), bf2f(h4.w)};
    float aw[8];
#pragma unroll
    for (int j = 0; j < 8; j++) aw[j] = bf2f(w8.u[j]);
#pragma unroll
    for (int i = 0; i < 4; i++)
#pragma unroll
      for (int j = 0; j < 8; j++) acc[i][j] += ah[i] * aw[j];
  }

  float4 bb0 = *(const float4*)&b_ae2[j0 + tj * 8];
  float4 bb1 = *(const float4*)&b_ae2[j0 + tj * 8 + 4];
  float bw[8] = {bb0.x, bb0.y, bb0.z, bb0.w, bb1.x, bb1.y, bb1.z, bb1.w};
#pragma unroll
  for (int i = 0; i < 4; i++)
#pragma unroll
    for (int j = 0; j < 8; j++) acc[i][j] += bw[j];

  // store: thread's 8 j = one f node, c = 0..8 -> [f][b][c] uint4 per b
  int f = (j0 >> 3) + tj;
#pragma unroll
  for (int i = 0; i < 4; i++) {
    int b = tb * 4 + i;
    union { ushort u[8]; uint4 v; } pk;
#pragma unroll
    for (int j = 0; j < 8; j++) pk.u[j] = f2bf(acc[i][j]);
    zT4[(size_t)f * BB + b] = pk.v;
  }

  if (cred) {
#pragma unroll
    for (int i = 0; i < 4; i++) {
      float s = 0.f, q = 0.f;
#pragma unroll
      for (int j = 0; j < 8; j++) { s += acc[i][j]; q += acc[i][j] * acc[i][j]; }
      int b = tb * 4 + i;
      atomicAdd(&lred[b * 2], s);
      atomicAdd(&lred[b * 2 + 1], q);
    }
  }
  __syncthreads();
  if (tid < 256) atomicAdd(&red[tid], lred[tid]);
}

// ---------------- layer part 1: hfc = elu(s * groupLN(8x8 matmul(xe) + b1)) -------------
// zT/hfcT in [f][b][c] layout: one uint4 read + one uint4 write per thread.
__launch_bounds__(256)
__global__ void k_layer1(const ushort* __restrict__ xeT, const float* __restrict__ w1l,
                         const float* __restrict__ b1l, const uint4* __restrict__ zT4,
                         const float* __restrict__ red, uint4* __restrict__ hfcT4) {
  __shared__ __align__(16) float wsm[2][64];
  __shared__ float bsm[2][8];
  int tid = threadIdx.x;
  int fs = tid >> 7;
  int b = tid & 127;
  int f = blockIdx.x * 2 + fs;
  if (tid < 128) wsm[tid >> 6][tid & 63] = w1l[blockIdx.x * 128 + tid];
  if (tid >= 128 && tid < 144) {
    int q = tid - 128;
    bsm[q >> 3][q & 7] = b1l[blockIdx.x * 16 + q];
  }
  __syncthreads();
  float mu_ln = red[b * 2] * (1.f / FC);
  float var_ln = red[b * 2 + 1] * (1.f / FC) - mu_ln * mu_ln;
  float isg_ln = rsqrtf(var_ln + 1e-5f);

  float xv[8];
#pragma unroll
  for (int k = 0; k < 8; k++) xv[k] = bf2f(xeT[(f * 8 + k) * BB + b]);
  float acc[8];
#pragma unroll
  for (int c = 0; c < 8; c++) acc[c] = bsm[fs][c];
#pragma unroll
  for (int k = 0; k < 8; k++) {
    const float4* wp = (const float4*)&wsm[fs][k * 8];
    float4 w0 = wp[0], w1 = wp[1];
    acc[0] += xv[k] * w0.x; acc[1] += xv[k] * w0.y;
    acc[2] += xv[k] * w0.z; acc[3] += xv[k] * w0.w;
    acc[4] += xv[k] * w1.x; acc[5] += xv[k] * w1.y;
    acc[6] += xv[k] * w1.z; acc[7] += xv[k] * w1.w;
  }
  float mu = 0.f;
#pragma unroll
  for (int c = 0; c < 8; c++) mu += acc[c];
  mu *= 0.125f;
  float var = 0.f;
#pragma unroll
  for (int c = 0; c < 8; c++) { float d = acc[c] - mu; var += d * d; }
  var *= 0.125f;
  float sc = rsqrtf(var + 1e-5f);

  union { ushort u[8]; uint4 v; } zu;
  zu.v = zT4[(size_t)f * BB + b];
  union { ushort u[8]; uint4 v; } pk;
#pragma unroll
  for (int c = 0; c < 8; c++) {
    float v = (acc[c] - mu) * sc;
    float sv = 1.f / (1.f + expf(-(bf2f(zu.u[c]) - mu_ln) * isg_ln));
    float hv = sv * v;
    hv = hv > 0.f ? hv : expm1f(hv);
    pk.u[c] = f2bf(hv);
  }
  hfcT4[(size_t)f * BB + b] = pk.v;
}

// ---------------- layer part 2: xe = (fe? dot8(hfc[src], w3) : 0) + b3 + xe ----------------
// hfc gather = one dwordx4 per lane ([g][b][0..8]).
__launch_bounds__(256)
__global__ void k_layer2(const uint4* __restrict__ hfcT4, const float* __restrict__ w3l,
                         const float* __restrict__ b3l, const int* __restrict__ map,
                         const int* __restrict__ src, ushort* __restrict__ xeT) {
  __shared__ float wsm[2][8];
  int tid = threadIdx.x;
  int es = tid >> 7;
  int b = tid & 127;
  int e = blockIdx.x * 2 + es;
  if (tid < 16) {
    int q = tid;
    int ee = blockIdx.x * 2 + (q >> 3);
    int ii = map[ee];
    wsm[q >> 3][q & 7] = (ii >= 0) ? w3l[ii * 8 + (q & 7)] : 0.f;
  }
  __syncthreads();
  int i = map[e];
  float rv = b3l[e] + bf2f(xeT[e * BB + b]);
  if (i >= 0) {
    int g = src[e] - NIN;
    union { ushort u[8]; uint4 v; } hv;
    hv.v = hfcT4[(size_t)g * BB + b];
    float a = 0.f;
#pragma unroll
    for (int c = 0; c < 8; c++) a += bf2f(hv.u[c]) * wsm[es][c];
    rv += a;
  }
  xeT[e * BB + b] = f2bf(rv);
}

// ---------------- output: out[b, 11000+j] = xe[b, 56000+j] / 4 ----------------
__global__ void k_out(const ushort* __restrict__ xeT, float* __restrict__ out) {
  __shared__ float t[32][33];
  int j0 = blockIdx.x * 32, b0 = blockIdx.y * 32;
  int tx = threadIdx.x, ty = threadIdx.y;
#pragma unroll
  for (int s2 = 0; s2 < 4; s2++) {
    int j = j0 + ty + s2 * 8;
    if (j < 1000) t[ty + s2 * 8][tx] = bf2f(xeT[(FC + j) * BB + b0 + tx]);
  }
  __syncthreads();
#pragma unroll
  for (int s2 = 0; s2 < 4; s2++) {
    int b = b0 + ty + s2 * 8;
    int j = j0 + tx;
    if (j < 1000) out[b * NN + 11000 + j] = t[tx][ty + s2 * 8] * 0.25f;
  }
}

extern "C" void kernel_launch(void* const* d_in, const int* in_sizes, int n_in,
                              void* d_out, int out_size, void* d_ws, size_t ws_size,
                              hipStream_t stream) {
  const float* x = (const float*)d_in[0];
  const float* W_ae1 = (const float*)d_in[1];
  const float* b_ae1 = (const float*)d_in[2];
  const float* W_ae2 = (const float*)d_in[3];
  const float* b_ae2 = (const float*)d_in[4];
  const float* w1_vals = (const float*)d_in[5];
  const float* b1 = (const float*)d_in[6];
  const float* w3_vals = (const float*)d_in[7];
  const float* b3 = (const float*)d_in[8];
  const int* src = (const int*)d_in[9];
  const int* w3_cols = (const int*)d_in[14];

  int nnz3 = in_sizes[13];
  int n_fe = nnz3 / 8;

  // Workspace (f32 slot offsets); all uint4 regions 16B-aligned (offsets %4==0).
  float* W = (float*)d_ws;
  float* h_raw = W + 0;                   // 12,800  [j*128+b]
  float* red = W + 12800;                 // 256
  ushort* hbf = (ushort*)(W + 13056);     // 12,800 bf16 = 6,400 -> ends 19,456
  int* map = (int*)(W + 19456);           // 57,000 ints -> ends 76,456
  float* xT = W + 76800;                  // 1,536,000 -> ends 1,612,800
  ushort* xeT = (ushort*)(W + 1612800);   // 7,296,000 bf16 = 3,648,000 -> ends 5,260,800
  uint4* zT4 = (uint4*)(W + 5260800);     // 7,168,000 bf16 = 3,584,000 -> ends 8,844,800
  uint4* hfcT4 = (uint4*)(W + 8844800);   // 3,584,000 -> ends 12,428,800
  ushort* w2b = (ushort*)(W + 12428800);  // 5,600,000 bf16 = 2,800,000 -> ends 15,228,800

  hipMemsetAsync(h_raw, 0, 13056 * sizeof(float), stream);  // h_raw + red
  hipMemsetAsync(map, 0xFF, EE * sizeof(int), stream);
  hipMemsetAsync(d_out, 0, (size_t)out_size * sizeof(float), stream);

  k_transpose<<<dim3(NN / 32, BB / 32), dim3(32, 8), 0, stream>>>(x, xT);
  k_w2bf<<<(LAT * FC / 8 + 255) / 256, 256, 0, stream>>>(W_ae2, w2b);
  k_ae1<<<dim3(25, 40), 128, 0, stream>>>(xT, W_ae1, h_raw);
  k_build_xe<<<(EE * BB) / 256, 256, 0, stream>>>(xT, src, xeT);
  k_map<<<(n_fe + 255) / 256, 256, 0, stream>>>(w3_cols, map, n_fe);
  k_elu<<<50, 256, 0, stream>>>(h_raw, b_ae1, hbf);
  k_ae2<<<438, 512, 0, stream>>>(hbf, w2b, b_ae2, zT4, red);
  for (int l = 0; l < 4; l++) {
    k_layer1<<<NFN / 2, 256, 0, stream>>>(xeT, w1_vals + (size_t)l * 448000,
                                          b1 + (size_t)l * FC, zT4, red, hfcT4);
    k_layer2<<<EE / 2, 256, 0, stream>>>(hfcT4, w3_vals + (size_t)l * nnz3,
                                         b3 + (size_t)l * EE, map, src, xeT);
  }
  k_out<<<dim3(32, 4), dim3(32, 8), 0, stream>>>(xeT, (float*)d_out);
}

// Round 9
// 337.382 us; speedup vs baseline: 1.1646x; 1.0792x over previous
//
#include <hip/hip_runtime.h>
#include <hip/hip_bf16.h>
#include <math.h>

#define BB 128
#define NN 12000
#define NIN 4000
#define NFN 7000
#define NOMIC 3600
#define FC 56000
#define EE 57000
#define LAT 100

typedef __hip_bfloat16 bf16;

__device__ __forceinline__ ushort f2bf(float f) {
  bf16 h = __float2bfloat16(f);
  return *(ushort*)&h;
}
__device__ __forceinline__ float bf2f(ushort u) {
  bf16 h = *(bf16*)&u;
  return __bfloat162float(h);
}

// ---------------- transpose x (B,N) -> xT (N,B) ----------------
__global__ void k_transpose(const float* __restrict__ x, float* __restrict__ xT) {
  __shared__ float t[32][33];
  int n0 = blockIdx.x * 32, b0 = blockIdx.y * 32;
  int tx = threadIdx.x, ty = threadIdx.y;
#pragma unroll
  for (int s = 0; s < 4; s++) {
    int b = b0 + ty + s * 8;
    int n = n0 + tx;
    t[ty + s * 8][tx] = x[b * NN + n];
  }
  __syncthreads();
#pragma unroll
  for (int s = 0; s < 4; s++) {
    int n = n0 + ty + s * 8;
    int b = b0 + tx;
    xT[n * BB + b] = t[tx][ty + s * 8];
  }
}

// ---------------- AE layer 1: h[j*128+b], split-K (80 chunks of 45) ----------------
__global__ void k_ae1(const float* __restrict__ xT, const float* __restrict__ W1,
                      float* __restrict__ h) {
  int b = threadIdx.x;
  int j0 = blockIdx.x * 4;
  int k0 = blockIdx.y * 45;
  float acc0 = 0.f, acc1 = 0.f, acc2 = 0.f, acc3 = 0.f;
  const float* xp = &xT[(size_t)k0 * BB + b];
  const float* wp = &W1[(size_t)k0 * LAT + j0];
#pragma unroll 5
  for (int kk = 0; kk < 45; kk++) {
    float xv = xp[kk * BB];
    float4 w = *(const float4*)(wp + kk * LAT);
    acc0 += xv * w.x; acc1 += xv * w.y; acc2 += xv * w.z; acc3 += xv * w.w;
  }
  atomicAdd(&h[(j0 + 0) * BB + b], acc0);
  atomicAdd(&h[(j0 + 1) * BB + b], acc1);
  atomicAdd(&h[(j0 + 2) * BB + b], acc2);
  atomicAdd(&h[(j0 + 3) * BB + b], acc3);
}

// ---------------- W2 fp32 -> bf16 (one-time, layout unchanged [k][j]) ----------------
__global__ void k_w2bf(const float* __restrict__ W2, ushort* __restrict__ w2b) {
  int i = (blockIdx.x * 256 + threadIdx.x) * 8;
  if (i >= LAT * FC) return;
  float4 a0 = *(const float4*)&W2[i];
  float4 a1 = *(const float4*)&W2[i + 4];
  union { ushort u[8]; uint4 v; } p;
  p.u[0] = f2bf(a0.x); p.u[1] = f2bf(a0.y); p.u[2] = f2bf(a0.z); p.u[3] = f2bf(a0.w);
  p.u[4] = f2bf(a1.x); p.u[5] = f2bf(a1.y); p.u[6] = f2bf(a1.z); p.u[7] = f2bf(a1.w);
  *(uint4*)&w2b[i] = p.v;
}

// ---------------- elu(h + b_ae1) -> bf16 hbf ----------------
__global__ void k_elu(const float* __restrict__ h, const float* __restrict__ b_ae1,
                      ushort* __restrict__ hbf) {
  int i = blockIdx.x * 256 + threadIdx.x;  // 12800 total
  float v = h[i] + b_ae1[i >> 7];
  hbf[i] = f2bf(v > 0.f ? v : expm1f(v));
}

// ---------------- build xeT (bf16) from xT / src ----------------
__global__ void k_build_xe(const float* __restrict__ xT, const int* __restrict__ src,
                           ushort* __restrict__ xeT) {
  int idx = blockIdx.x * 256 + threadIdx.x;
  if (idx >= EE * BB) return;
  int e = idx >> 7, b = idx & 127;
  int s = src[e];
  xeT[idx] = (s < NOMIC) ? f2bf(0.f) : f2bf(xT[s * BB + b]);
}

// ---------------- map[e] = fe-position i (else -1, pre-set by memset 0xFF) ----------------
__global__ void k_map(const int* __restrict__ w3_cols, int* __restrict__ map, int n_fe) {
  int i = blockIdx.x * 256 + threadIdx.x;
  if (i < n_fe) map[w3_cols[i * 8]] = i;
}

// ---------------- AE layer 2 GEMM: zT[f][b][c](bf16) = h_elu @ W2 + b2, + LN sums -------
// Tile 128b x 64j, 256 thr = 8 tj x 32 tb, 4b x 8j per thread. Grid 875 exact
// (3.4 blocks/CU, no tail). bf16 W2 + bf16 hh (25.6 KB LDS).
__launch_bounds__(256)
__global__ void k_ae2(const ushort* __restrict__ hbf, const ushort* __restrict__ w2b,
                      const float* __restrict__ b_ae2, uint4* __restrict__ zT4,
                      float* __restrict__ red) {
  __shared__ __align__(16) ushort hh[LAT * BB];  // [k*128+b] bf16, 25.6 KB
  __shared__ float lred[256];
  int tid = threadIdx.x;
  lred[tid] = 0.f;
  for (int i = tid * 8; i < LAT * BB; i += 256 * 8)
    *(uint4*)&hh[i] = *(const uint4*)&hbf[i];
  __syncthreads();

  int tj = tid >> 5;   // 0..7  -> 8 j (= 1 f node) each
  int tb = tid & 31;   // 0..31 -> 4 b each
  int j0 = blockIdx.x * 64;  // 875 * 64 = 56000 exact

  float acc[4][8];
#pragma unroll
  for (int i = 0; i < 4; i++)
#pragma unroll
    for (int j = 0; j < 8; j++) acc[i][j] = 0.f;

  const ushort* hp = &hh[tb * 4];
  const ushort* wp = &w2b[j0 + tj * 8];
#pragma unroll 4
  for (int k = 0; k < LAT; k++) {
    ushort4 h4 = *(const ushort4*)(hp + k * BB);
    union { ushort u[8]; uint4 v; } w8;
    w8.v = *(const uint4*)(wp + (size_t)k * FC);
    float ah[4] = {bf2f(h4.x), bf2f(h4.y), bf2f(h4.z), bf2f(h4.w)};
    float aw[8];
#pragma unroll
    for (int j = 0; j < 8; j++) aw[j] = bf2f(w8.u[j]);
#pragma unroll
    for (int i = 0; i < 4; i++)
#pragma unroll
      for (int j = 0; j < 8; j++) acc[i][j] += ah[i] * aw[j];
  }

  float4 bb0 = *(const float4*)&b_ae2[j0 + tj * 8];
  float4 bb1 = *(const float4*)&b_ae2[j0 + tj * 8 + 4];
  float bw[8] = {bb0.x, bb0.y, bb0.z, bb0.w, bb1.x, bb1.y, bb1.z, bb1.w};
#pragma unroll
  for (int i = 0; i < 4; i++)
#pragma unroll
    for (int j = 0; j < 8; j++) acc[i][j] += bw[j];

  // store: thread's 8 j = one f node -> [f][b][c] uint4 per b
  int f = blockIdx.x * 8 + tj;
#pragma unroll
  for (int i = 0; i < 4; i++) {
    int b = tb * 4 + i;
    union { ushort u[8]; uint4 v; } pk;
#pragma unroll
    for (int j = 0; j < 8; j++) pk.u[j] = f2bf(acc[i][j]);
    zT4[(size_t)f * BB + b] = pk.v;
  }

  // LN partial sums (tiles exact -> every j counted once)
#pragma unroll
  for (int i = 0; i < 4; i++) {
    float s = 0.f, q = 0.f;
#pragma unroll
    for (int j = 0; j < 8; j++) { s += acc[i][j]; q += acc[i][j] * acc[i][j]; }
    int b = tb * 4 + i;
    atomicAdd(&lred[b * 2], s);
    atomicAdd(&lred[b * 2 + 1], q);
  }
  __syncthreads();
  atomicAdd(&red[tid], lred[tid]);
}

// ---------------- layer part 1: hfc = elu(s * groupLN(8x8 matmul(xe) + b1)) -------------
// 4 f per block x 64 lanes x 2 b per thread (two independent chains).
__launch_bounds__(256)
__global__ void k_layer1(const ushort* __restrict__ xeT, const float* __restrict__ w1l,
                         const float* __restrict__ b1l, const uint4* __restrict__ zT4,
                         const float* __restrict__ red, uint4* __restrict__ hfcT4) {
  __shared__ __align__(16) float wsm[4][64];
  __shared__ float bsm[4][8];
  int tid = threadIdx.x;
  int fs = tid >> 6;   // 0..3
  int lane = tid & 63;
  int f = blockIdx.x * 4 + fs;
  wsm[tid >> 6][tid & 63] = w1l[blockIdx.x * 256 + tid];
  if (tid < 32) bsm[tid >> 3][tid & 7] = b1l[blockIdx.x * 32 + tid];
  __syncthreads();

#pragma unroll
  for (int half = 0; half < 2; half++) {
    int b = lane + half * 64;
    float mu_ln = red[b * 2] * (1.f / FC);
    float var_ln = red[b * 2 + 1] * (1.f / FC) - mu_ln * mu_ln;
    float isg_ln = rsqrtf(var_ln + 1e-5f);

    float xv[8];
#pragma unroll
    for (int k = 0; k < 8; k++) xv[k] = bf2f(xeT[(f * 8 + k) * BB + b]);
    float acc[8];
#pragma unroll
    for (int c = 0; c < 8; c++) acc[c] = bsm[fs][c];
#pragma unroll
    for (int k = 0; k < 8; k++) {
      const float4* wp = (const float4*)&wsm[fs][k * 8];
      float4 w0 = wp[0], w1 = wp[1];
      acc[0] += xv[k] * w0.x; acc[1] += xv[k] * w0.y;
      acc[2] += xv[k] * w0.z; acc[3] += xv[k] * w0.w;
      acc[4] += xv[k] * w1.x; acc[5] += xv[k] * w1.y;
      acc[6] += xv[k] * w1.z; acc[7] += xv[k] * w1.w;
    }
    float mu = 0.f;
#pragma unroll
    for (int c = 0; c < 8; c++) mu += acc[c];
    mu *= 0.125f;
    float var = 0.f;
#pragma unroll
    for (int c = 0; c < 8; c++) { float d = acc[c] - mu; var += d * d; }
    var *= 0.125f;
    float sc = rsqrtf(var + 1e-5f);

    union { ushort u[8]; uint4 v; } zu;
    zu.v = zT4[(size_t)f * BB + b];
    union { ushort u[8]; uint4 v; } pk;
#pragma unroll
    for (int c = 0; c < 8; c++) {
      float v = (acc[c] - mu) * sc;
      float sv = 1.f / (1.f + expf(-(bf2f(zu.u[c]) - mu_ln) * isg_ln));
      float hv = sv * v;
      hv = hv > 0.f ? hv : expm1f(hv);
      pk.u[c] = f2bf(hv);
    }
    hfcT4[(size_t)f * BB + b] = pk.v;
  }
}

// ---------------- layer part 2: xe = (fe? dot8(hfc[src], w3) : 0) + b3 + xe ----------------
// 4 edges per block x 64 lanes x 2 b per thread (two independent gather chains).
__launch_bounds__(256)
__global__ void k_layer2(const uint4* __restrict__ hfcT4, const float* __restrict__ w3l,
                         const float* __restrict__ b3l, const int* __restrict__ map,
                         const int* __restrict__ src, ushort* __restrict__ xeT) {
  __shared__ float wsm[4][8];
  int tid = threadIdx.x;
  int es = tid >> 6;   // 0..3
  int lane = tid & 63;
  int e = blockIdx.x * 4 + es;
  if (tid < 32) {
    int q = tid;
    int ee = blockIdx.x * 4 + (q >> 3);
    int ii = map[ee];
    wsm[q >> 3][q & 7] = (ii >= 0) ? w3l[ii * 8 + (q & 7)] : 0.f;
  }
  __syncthreads();
  int i = map[e];
  int g = src[e] - NIN;
  float be = b3l[e];
#pragma unroll
  for (int half = 0; half < 2; half++) {
    int b = lane + half * 64;
    float rv = be + bf2f(xeT[e * BB + b]);
    if (i >= 0) {
      union { ushort u[8]; uint4 v; } hv;
      hv.v = hfcT4[(size_t)g * BB + b];
      float a = 0.f;
#pragma unroll
      for (int c = 0; c < 8; c++) a += bf2f(hv.u[c]) * wsm[es][c];
      rv += a;
    }
    xeT[e * BB + b] = f2bf(rv);
  }
}

// ---------------- output: out[b, 11000+j] = xe[b, 56000+j] / 4 ----------------
__global__ void k_out(const ushort* __restrict__ xeT, float* __restrict__ out) {
  __shared__ float t[32][33];
  int j0 = blockIdx.x * 32, b0 = blockIdx.y * 32;
  int tx = threadIdx.x, ty = threadIdx.y;
#pragma unroll
  for (int s2 = 0; s2 < 4; s2++) {
    int j = j0 + ty + s2 * 8;
    if (j < 1000) t[ty + s2 * 8][tx] = bf2f(xeT[(FC + j) * BB + b0 + tx]);
  }
  __syncthreads();
#pragma unroll
  for (int s2 = 0; s2 < 4; s2++) {
    int b = b0 + ty + s2 * 8;
    int j = j0 + tx;
    if (j < 1000) out[b * NN + 11000 + j] = t[tx][ty + s2 * 8] * 0.25f;
  }
}

extern "C" void kernel_launch(void* const* d_in, const int* in_sizes, int n_in,
                              void* d_out, int out_size, void* d_ws, size_t ws_size,
                              hipStream_t stream) {
  const float* x = (const float*)d_in[0];
  const float* W_ae1 = (const float*)d_in[1];
  const float* b_ae1 = (const float*)d_in[2];
  const float* W_ae2 = (const float*)d_in[3];
  const float* b_ae2 = (const float*)d_in[4];
  const float* w1_vals = (const float*)d_in[5];
  const float* b1 = (const float*)d_in[6];
  const float* w3_vals = (const float*)d_in[7];
  const float* b3 = (const float*)d_in[8];
  const int* src = (const int*)d_in[9];
  const int* w3_cols = (const int*)d_in[14];

  int nnz3 = in_sizes[13];
  int n_fe = nnz3 / 8;

  // Workspace (f32 slot offsets); all uint4 regions 16B-aligned.
  float* W = (float*)d_ws;
  float* h_raw = W + 0;                   // 12,800  [j*128+b]
  float* red = W + 12800;                 // 256
  ushort* hbf = (ushort*)(W + 13056);     // 6,400 -> ends 19,456
  int* map = (int*)(W + 19456);           // 57,000 ints -> ends 76,456
  float* xT = W + 76800;                  // 1,536,000 -> ends 1,612,800
  ushort* xeT = (ushort*)(W + 1612800);   // 3,648,000 -> ends 5,260,800
  uint4* zT4 = (uint4*)(W + 5260800);     // 3,584,000 -> ends 8,844,800
  uint4* hfcT4 = (uint4*)(W + 8844800);   // 3,584,000 -> ends 12,428,800
  ushort* w2b = (ushort*)(W + 12428800);  // 2,800,000 -> ends 15,228,800

  hipMemsetAsync(h_raw, 0, 13056 * sizeof(float), stream);  // h_raw + red
  hipMemsetAsync(map, 0xFF, EE * sizeof(int), stream);
  hipMemsetAsync(d_out, 0, (size_t)out_size * sizeof(float), stream);

  k_transpose<<<dim3(NN / 32, BB / 32), dim3(32, 8), 0, stream>>>(x, xT);
  k_w2bf<<<(LAT * FC / 8 + 255) / 256, 256, 0, stream>>>(W_ae2, w2b);
  k_ae1<<<dim3(25, 80), 128, 0, stream>>>(xT, W_ae1, h_raw);
  k_build_xe<<<(EE * BB) / 256, 256, 0, stream>>>(xT, src, xeT);
  k_map<<<(n_fe + 255) / 256, 256, 0, stream>>>(w3_cols, map, n_fe);
  k_elu<<<50, 256, 0, stream>>>(h_raw, b_ae1, hbf);
  k_ae2<<<875, 256, 0, stream>>>(hbf, w2b, b_ae2, zT4, red);
  for (int l = 0; l < 4; l++) {
    k_layer1<<<NFN / 4, 256, 0, stream>>>(xeT, w1_vals + (size_t)l * 448000,
                                          b1 + (size_t)l * FC, zT4, red, hfcT4);
    k_layer2<<<EE / 4, 256, 0, stream>>>(hfcT4, w3_vals + (size_t)l * nnz3,
                                         b3 + (size_t)l * EE, map, src, xeT);
  }
  k_out<<<dim3(32, 4), dim3(32, 8), 0, stream>>>(xeT, (float*)d_out);
}